// Round 2
// 553.554 us; speedup vs baseline: 1.2469x; 1.2469x over previous
//
#include <hip/hip_runtime.h>
#include <stdint.h>

#define BB 64
#define TT 4096
#define DD 256
#define HH 341
#define HP 384      // padded H: 24 tiles of 16
#define NEGV (-1e9f)

typedef __attribute__((ext_vector_type(8))) short short8;
typedef __attribute__((ext_vector_type(4))) float f32x4;

// ---------------------------------------------------------------- utilities

// A&S 7.1.26 erf (|abs err| <= 1.5e-7) -> exact-GELU substitute.
// Error budget: gelu err ~ |x|*7.5e-8, far below the bf16-split score error.
__device__ inline float gelu_fast(float x) {
  const float y = fabsf(x) * 0.70710678118654752440f;
  const float t = __builtin_amdgcn_rcpf(fmaf(0.3275911f, y, 1.0f));
  float p = fmaf(1.061405429f, t, -1.453152027f);
  p = fmaf(p, t, 1.421413741f);
  p = fmaf(p, t, -0.284496736f);
  p = fmaf(p, t, 0.254829592f);
  p *= t;
  const float e = __expf(-y * y);
  float er = fmaf(-p, e, 1.0f);          // erf(|x|/sqrt(2))
  er = (x < 0.0f) ? -er : er;
  return 0.5f * x * (1.0f + er);
}

__device__ inline uint32_t rotl32(uint32_t x, int d) { return (x << d) | (x >> (32 - d)); }

// JAX threefry2x32, jax_threefry_partitionable=True (verified passing in R1):
// counter = (hi=0, lo=j); key(42) -> (0,42); output = x0 ^ x1.
__device__ inline uint32_t threefry_bits(uint32_t j) {
  const uint32_t K0 = 0u, K1 = 42u;
  const uint32_t K2 = K0 ^ K1 ^ 0x1BD11BDAu;
  uint32_t x0 = 0u, x1 = j;
  x0 += K0; x1 += K1;
#define TF_RND(r) { x0 += x1; x1 = rotl32(x1, r); x1 ^= x0; }
  TF_RND(13) TF_RND(15) TF_RND(26) TF_RND(6)
  x0 += K1; x1 += K2 + 1u;
  TF_RND(17) TF_RND(29) TF_RND(16) TF_RND(24)
  x0 += K2; x1 += K0 + 2u;
  TF_RND(13) TF_RND(15) TF_RND(26) TF_RND(6)
  x0 += K0; x1 += K1 + 3u;
  TF_RND(17) TF_RND(29) TF_RND(16) TF_RND(24)
  x0 += K1; x1 += K2 + 4u;
  TF_RND(13) TF_RND(15) TF_RND(26) TF_RND(6)
  x0 += K2; x1 += K0 + 5u;
#undef TF_RND
  return x0 ^ x1;
}

// round-to-nearest-even fp32 -> bf16 split: x = hi + lo (+ ~2^-17 residual)
__device__ inline void bf16split(float x, short& hi, short& lo) {
  uint32_t u = __float_as_uint(x);
  uint32_t h = (u + 0x7FFFu + ((u >> 16) & 1u)) >> 16;
  float rem = x - __uint_as_float(h << 16);
  uint32_t ur = __float_as_uint(rem);
  uint32_t l = (ur + 0x7FFFu + ((ur >> 16) & 1u)) >> 16;
  hi = (short)h; lo = (short)l;
}

__device__ inline float bred_sum(float v, volatile float* tmp, int tid) {
#pragma unroll
  for (int o = 32; o; o >>= 1) v += __shfl_xor(v, o, 64);
  __syncthreads();
  if ((tid & 63) == 0) tmp[tid >> 6] = v;
  __syncthreads();
  return tmp[0] + tmp[1] + tmp[2] + tmp[3];
}

__device__ inline float bred_max(float v, volatile float* tmp, int tid) {
#pragma unroll
  for (int o = 32; o; o >>= 1) v = fmaxf(v, __shfl_xor(v, o, 64));
  __syncthreads();
  if ((tid & 63) == 0) tmp[tid >> 6] = v;
  __syncthreads();
  return fmaxf(fmaxf(tmp[0], tmp[1]), fmaxf(tmp[2], tmp[3]));
}

// joint (a,b) sum-reduce: one pair of barriers for two values
__device__ inline void bred_sum2(float& a, float& b, volatile float* tmp, int tid) {
#pragma unroll
  for (int o = 32; o; o >>= 1) { a += __shfl_xor(a, o, 64); b += __shfl_xor(b, o, 64); }
  __syncthreads();
  if ((tid & 63) == 0) { int w2 = (tid >> 6) * 2; tmp[w2] = a; tmp[w2 + 1] = b; }
  __syncthreads();
  a = tmp[0] + tmp[2] + tmp[4] + tmp[6];
  b = tmp[1] + tmp[3] + tmp[5] + tmp[7];
}

// joint (a,b,c) int sum-reduce
__device__ inline void bred3_i(int& a, int& b, int& c, volatile int* tmp, int tid) {
#pragma unroll
  for (int o = 32; o; o >>= 1) {
    a += __shfl_xor(a, o, 64);
    b += __shfl_xor(b, o, 64);
    c += __shfl_xor(c, o, 64);
  }
  __syncthreads();
  if ((tid & 63) == 0) { int w3 = (tid >> 6) * 3; tmp[w3] = a; tmp[w3 + 1] = b; tmp[w3 + 2] = c; }
  __syncthreads();
  a = tmp[0] + tmp[3] + tmp[6] + tmp[9];
  b = tmp[1] + tmp[4] + tmp[7] + tmp[10];
  c = tmp[2] + tmp[5] + tmp[8] + tmp[11];
}

// ------------------- kernel 0: transpose + bf16-split W1 -> W1T hi/lo in ws
// W1T layout: [HP][DD] bf16 row-major (h-major, k contiguous); h>=HH rows are 0.

__global__ __launch_bounds__(256) void k0_prep(const float* __restrict__ W1,
                                               short* __restrict__ Whi,
                                               short* __restrict__ Wlo) {
  int idx = blockIdx.x * 256 + threadIdx.x;   // < HP*DD
  int h = idx >> 8, k = idx & 255;
  float v = (h < HH) ? W1[k * HH + h] : 0.0f;
  short hi, lo;
  bf16split(v, hi, lo);
  Whi[idx] = hi;
  Wlo[idx] = lo;
}

// ------------------- kernel 1: mask+LN+split-bf16 MFMA MLP -> scores
// 512 threads (8 waves) per 64-row tile; each wave owns 3 h-tiles
// (24 tiles / 8 waves) and all 4 M-tiles. 64 KB LDS -> 2 blocks/CU =
// 16 waves/CU (vs 4-wave version's ~4.9 waves/CU, 15% occupancy).
// A (LN'd activations) stored in LDS in MFMA A-fragment order:
// slot(mt,k0,q,i) = mt*512 + k0*64 + q*16 + (i^k0)   (16B units, XOR de-bank)
// holds A[row=mt*16+i][k = k0*32 + q*8 + j], j=0..7.

__global__ __launch_bounds__(512, 4) void k1_mfma(
    const float* __restrict__ emb, const float* __restrict__ attn,
    const float* __restrict__ gamma, const float* __restrict__ beta,
    const short* __restrict__ Whi, const float* __restrict__ b1,
    const float* __restrict__ W2, const float* __restrict__ b2,
    float* __restrict__ scores) {
  __shared__ short Ahi[16384];   // 32 KB
  __shared__ short Alo[16384];   // 32 KB  (total 64 KB exactly)

  const int bid = blockIdx.x;
  const int b = bid >> 6;             // 64 row-tiles per batch row
  const int t0 = (bid & 63) * 64;
  const int tid = threadIdx.x;
  const int w = tid >> 6;             // wave id 0..7
  const int lane = tid & 63;

  // prefix mask: first row masked -> whole 64-row tile masked
  if (attn[(size_t)b * TT + t0] == 0.0f) {
    if (tid < 64) scores[(size_t)b * TT + t0 + tid] = NEGV;
    return;
  }

  // ---------------- prologue: LN 2 rows per wave-iteration, write A frags
  {
    const int half = lane >> 5;        // which of the 2 rows
    const int g = lane & 31;           // 8-col group within row
    const int k0g = g >> 2, qg = g & 3;
    float gg[8], bb[8];
#pragma unroll
    for (int j = 0; j < 8; ++j) { gg[j] = gamma[g * 8 + j]; bb[j] = beta[g * 8 + j]; }

    for (int it = 0; it < 4; ++it) {
      const int il = w * 8 + it * 2 + half;          // local row 0..63
      const size_t rowoff = (size_t)b * TT + t0 + il;
      const float a = attn[rowoff];
      const float* ep = emb + rowoff * DD + g * 8;
      float x[8];
      {
        float4 xA = *(const float4*)ep;
        float4 xB = *(const float4*)(ep + 4);
        x[0] = xA.x * a; x[1] = xA.y * a; x[2] = xA.z * a; x[3] = xA.w * a;
        x[4] = xB.x * a; x[5] = xB.y * a; x[6] = xB.z * a; x[7] = xB.w * a;
      }
      float s = 0.f, ss = 0.f;
#pragma unroll
      for (int j = 0; j < 8; ++j) { s += x[j]; ss += x[j] * x[j]; }
#pragma unroll
      for (int o = 16; o; o >>= 1) { s += __shfl_xor(s, o, 32); ss += __shfl_xor(ss, o, 32); }
      const float mu = s * (1.0f / DD);
      const float rs = 1.0f / sqrtf(ss * (1.0f / DD) - mu * mu + 1e-5f);

      short8 h8, l8;
#pragma unroll
      for (int j = 0; j < 8; ++j) {
        float y = (x[j] - mu) * rs * gg[j] + bb[j];
        short hi, lo;
        bf16split(y, hi, lo);
        h8[j] = hi; l8[j] = lo;
      }
      const int i15 = il & 15, mt = il >> 4;
      const int slot = mt * 512 + k0g * 64 + qg * 16 + (i15 ^ k0g);
      *(short8*)&Ahi[slot * 8] = h8;
      *(short8*)&Alo[slot * 8] = l8;
    }
  }
  __syncthreads();

  // ---------------- K-loop: wave w owns h-tiles {3w .. 3w+2}, all 4 M-tiles
  const int r = lane & 15, q = lane >> 4;
  f32x4 acc[3][4];
#pragma unroll
  for (int j = 0; j < 3; ++j)
#pragma unroll
    for (int mt = 0; mt < 4; ++mt) acc[j][mt] = (f32x4){0.f, 0.f, 0.f, 0.f};

  int hb[3];
#pragma unroll
  for (int j = 0; j < 3; ++j) hb[j] = ((w * 3 + j) * 16 + r) * 256 + q * 8;

  for (int k0 = 0; k0 < 8; ++k0) {
    short8 ahi[4], alo[4];
#pragma unroll
    for (int mt = 0; mt < 4; ++mt) {
      const int slot = mt * 512 + k0 * 64 + q * 16 + (r ^ k0);
      ahi[mt] = *(const short8*)&Ahi[slot * 8];
      alo[mt] = *(const short8*)&Alo[slot * 8];
    }
#pragma unroll
    for (int j = 0; j < 3; ++j) {
      const short* bp = Whi + hb[j] + k0 * 32;
      short8 bhi = *(const short8*)bp;
      short8 blo = *(const short8*)(bp + HP * DD);   // Wlo follows Whi
#pragma unroll
      for (int mt = 0; mt < 4; ++mt) {
        acc[j][mt] = __builtin_amdgcn_mfma_f32_16x16x32_bf16(ahi[mt], bhi, acc[j][mt], 0, 0, 0);
        acc[j][mt] = __builtin_amdgcn_mfma_f32_16x16x32_bf16(ahi[mt], blo, acc[j][mt], 0, 0, 0);
        acc[j][mt] = __builtin_amdgcn_mfma_f32_16x16x32_bf16(alo[mt], bhi, acc[j][mt], 0, 0, 0);
      }
    }
  }

  // ---------------- epilogue: gelu -> *W2; sum over j per-lane FIRST,
  // then one 4-level shfl reduce per (mt,rr) (64 shfl/thread vs 384 before).
  // C/D layout: col(h within tile) = lane&15, row = q*4 + reg  [m89/m91]
  float part[4][4];
#pragma unroll
  for (int mt = 0; mt < 4; ++mt)
#pragma unroll
    for (int rr = 0; rr < 4; ++rr) part[mt][rr] = 0.f;

#pragma unroll
  for (int j = 0; j < 3; ++j) {
    const int h = (w * 3 + j) * 16 + r;
    const float w2v = (h < HH) ? W2[h] : 0.f;
    const float b1v = (h < HH) ? b1[h] : 0.f;
#pragma unroll
    for (int mt = 0; mt < 4; ++mt)
#pragma unroll
      for (int rr = 0; rr < 4; ++rr)
        part[mt][rr] += gelu_fast(acc[j][mt][rr] + b1v) * w2v;
  }

  float sacc[4][4];
#pragma unroll
  for (int mt = 0; mt < 4; ++mt)
#pragma unroll
    for (int rr = 0; rr < 4; ++rr) {
      float v = part[mt][rr];
      v += __shfl_xor(v, 1, 64);
      v += __shfl_xor(v, 2, 64);
      v += __shfl_xor(v, 4, 64);
      v += __shfl_xor(v, 8, 64);
      sacc[mt][rr] = v;
    }

  __syncthreads();                         // all waves done reading A from LDS
  float* sred = (float*)Ahi;               // overlap: 512 floats
  if (r == 0) {
#pragma unroll
    for (int mt = 0; mt < 4; ++mt)
#pragma unroll
      for (int rr = 0; rr < 4; ++rr)
        sred[w * 64 + mt * 16 + q * 4 + rr] = sacc[mt][rr];
  }
  __syncthreads();

  if (tid < 64) {
    float sc = b2[0];
#pragma unroll
    for (int ww = 0; ww < 8; ++ww) sc += sred[ww * 64 + tid];
    float a = attn[(size_t)b * TT + t0 + tid];
    scores[(size_t)b * TT + t0 + tid] = (a != 0.f) ? sc : NEGV;
  }
}

// ---------------- kernel 2: per batch row — entmax15, gumbel top-k, z/g/tv
// Newton for entmax tau (18 rounds, joint f/g reduce) instead of 36-round
// bisection; 2-bit radix select (16 rounds, joint 3-counter reduce) instead
// of 32-round 1-bit. Exact same results: Newton on convex decreasing
// f(tau)=sum (x-tau)_+^2 from tau0=-1 (left of root) is monotone-convergent;
// tau* <= -1/64 guaranteed (sum d^2 = 1, support <= 4096 => d_max >= 1/64),
// so the clamp keeps g >= 1/64 > 0. Radix select is the identical integer
// algorithm with wider digits.

__global__ __launch_bounds__(256) void k2_select(
    const float* __restrict__ attn, float* __restrict__ out, float* __restrict__ row_tv) {
  __shared__ float gs[TT];
  __shared__ float ftmp[8];
  __shared__ int itmp[12];

  const int b = blockIdx.x, tid = threadIdx.x;
  const float* arow = attn + (size_t)b * TT;
  float* zrow = out + (size_t)b * TT;
  float* grow = out + (size_t)BB * TT + (size_t)b * TT;  // holds scores right now

  float x_loc[16], a_loc[16];
  uint32_t key_loc[16];
  float cnt = 0.0f, mx = -3.4e38f;
#pragma unroll
  for (int i = 0; i < 16; ++i) {
    int t = tid + i * 256;
    float s = grow[t];
    float a = arow[t];
    a_loc[i] = a;
    x_loc[i] = s;
    cnt += a;
    mx = fmaxf(mx, s);
    uint32_t bits = threefry_bits((uint32_t)(b * TT + t));
    float u = __uint_as_float(0x3F800000u | (bits >> 9)) - 1.0f;
    float gum = -logf(1e-6f - logf(u + 1e-6f));
    float pert = (a != 0.0f ? s : 0.0f) + gum;
    uint32_t fb = __float_as_uint(pert);
    uint32_t msk = ((int32_t)fb < 0) ? 0xFFFFFFFFu : 0x80000000u;
    key_loc[i] = fb ^ msk;
  }
  float t_eff = bred_sum(cnt, ftmp, tid);
  mx = bred_max(mx, ftmp, tid);

#pragma unroll
  for (int i = 0; i < 16; ++i) x_loc[i] = (x_loc[i] - mx) * 0.5f;

  // Newton for tau: f(tau) = sum (x-tau)_+^2, f'(tau) = -2 sum (x-tau)_+
  float tau = -1.0f;
  for (int it = 0; it < 18; ++it) {
    float f = 0.0f, g = 0.0f;
#pragma unroll
    for (int i = 0; i < 16; ++i) {
      float d = x_loc[i] - tau;
      if (d > 0.0f) { f = fmaf(d, d, f); g += d; }
    }
    bred_sum2(f, g, ftmp, tid);
    tau = fminf(tau + (f - 1.0f) / (2.0f * g), -0.015625f);
  }

  float kf = rintf(0.3f * t_eff);
  kf = fminf(fmaxf(kf, 1.0f), fmaxf(t_eff, 1.0f));
  int kk = (int)kf;

  // 2-bit MSD radix select for the k-th largest key
  uint32_t prefix = 0u;
  for (int bit = 30; bit >= 0; bit -= 2) {
    uint32_t ph = (prefix >> 2) >> bit;          // two-step shift: defined at bit=30
    int c1 = 0, c2 = 0, c3 = 0;
#pragma unroll
    for (int i = 0; i < 16; ++i) {
      uint32_t kb = key_loc[i];
      bool m = (((kb >> 2) >> bit) == ph);
      uint32_t d = (kb >> bit) & 3u;
      c1 += (int)(m && d >= 1u);
      c2 += (int)(m && d >= 2u);
      c3 += (int)(m && d == 3u);
    }
    bred3_i(c1, c2, c3, itmp, tid);
    uint32_t dig;
    if (c3 >= kk) dig = 3u;
    else if (c2 >= kk) { dig = 2u; kk -= c3; }
    else if (c1 >= kk) { dig = 1u; kk -= c2; }
    else { dig = 0u; kk -= c1; }
    prefix |= dig << bit;
  }
  const uint32_t thr = prefix;

#pragma unroll
  for (int i = 0; i < 16; ++i) {
    int t = tid + i * 256;
    float d = x_loc[i] - tau;
    float z = (d > 0.0f) ? d * d : 0.0f;
    z *= a_loc[i];
    float h = (key_loc[i] >= thr) ? a_loc[i] : 0.0f;
    float g = (h - z) + z;
    zrow[t] = z;
    gs[t] = g;
  }
  __syncthreads();

  float tvn = 0.0f, tvd = 0.0f;
#pragma unroll
  for (int i = 0; i < 16; ++i) {
    int t = tid + i * 256;
    grow[t] = gs[t];
    if (t > 0) {
      float valid = arow[t] * arow[t - 1];
      tvn += fabsf(gs[t] - gs[t - 1]) * valid;
      tvd += valid;
    }
  }
  tvn = bred_sum(tvn, ftmp, tid);
  tvd = bred_sum(tvd, ftmp, tid);
  if (tid == 0) row_tv[b] = tvn / fmaxf(tvd, 1.0f);
}

// ------------------------------------------------- kernel 3: reg scalar

__global__ __launch_bounds__(64) void k3_final(const float* __restrict__ row_tv,
                                               float* __restrict__ out) {
  float v = row_tv[threadIdx.x];
#pragma unroll
  for (int o = 32; o; o >>= 1) v += __shfl_xor(v, o, 64);
  if (threadIdx.x == 0) out[2 * BB * TT] = 0.1f * (v * (1.0f / BB));
}

// -------------------------------------------------------------- launcher

extern "C" void kernel_launch(void* const* d_in, const int* in_sizes, int n_in,
                              void* d_out, int out_size, void* d_ws, size_t ws_size,
                              hipStream_t stream) {
  const float* emb   = (const float*)d_in[0];
  const float* attn  = (const float*)d_in[1];
  const float* gamma = (const float*)d_in[2];
  const float* beta  = (const float*)d_in[3];
  const float* W1    = (const float*)d_in[4];
  const float* b1    = (const float*)d_in[5];
  const float* W2    = (const float*)d_in[6];
  const float* b2    = (const float*)d_in[7];
  float* out = (float*)d_out;

  float* row_tv = (float*)d_ws;                        // 64 floats
  short* Whi = (short*)((char*)d_ws + 512);            // [HP*DD] bf16 hi
  short* Wlo = Whi + HP * DD;                          // [HP*DD] bf16 lo

  k0_prep<<<dim3(HP * DD / 256), dim3(256), 0, stream>>>(W1, Whi, Wlo);
  k1_mfma<<<dim3(BB * TT / 64), dim3(512), 0, stream>>>(
      emb, attn, gamma, beta, Whi, b1, W2, b2, out + (size_t)BB * TT);
  k2_select<<<dim3(BB), dim3(256), 0, stream>>>(attn, out, row_tv);
  k3_final<<<dim3(1), dim3(64), 0, stream>>>(row_tv, out);
}

// Round 3
// 553.013 us; speedup vs baseline: 1.2481x; 1.0010x over previous
//
#include <hip/hip_runtime.h>
#include <stdint.h>

#define BB 64
#define TT 4096
#define DD 256
#define HH 341
#define HP 384      // padded H: 24 tiles of 16
#define NEGV (-1e9f)

typedef __attribute__((ext_vector_type(8))) short short8;
typedef __attribute__((ext_vector_type(4))) float f32x4;

// ---------------------------------------------------------------- utilities

// A&S 7.1.26 erf (|abs err| <= 1.5e-7) -> exact-GELU substitute.
__device__ inline float gelu_fast(float x) {
  const float y = fabsf(x) * 0.70710678118654752440f;
  const float t = __builtin_amdgcn_rcpf(fmaf(0.3275911f, y, 1.0f));
  float p = fmaf(1.061405429f, t, -1.453152027f);
  p = fmaf(p, t, 1.421413741f);
  p = fmaf(p, t, -0.284496736f);
  p = fmaf(p, t, 0.254829592f);
  p *= t;
  const float e = __expf(-y * y);
  float er = fmaf(-p, e, 1.0f);          // erf(|x|/sqrt(2))
  er = (x < 0.0f) ? -er : er;
  return 0.5f * x * (1.0f + er);
}

__device__ inline uint32_t rotl32(uint32_t x, int d) { return (x << d) | (x >> (32 - d)); }

// JAX threefry2x32, jax_threefry_partitionable=True (verified passing):
// counter = (hi=0, lo=j); key(42) -> (0,42); output = x0 ^ x1.
__device__ inline uint32_t threefry_bits(uint32_t j) {
  const uint32_t K0 = 0u, K1 = 42u;
  const uint32_t K2 = K0 ^ K1 ^ 0x1BD11BDAu;
  uint32_t x0 = 0u, x1 = j;
  x0 += K0; x1 += K1;
#define TF_RND(r) { x0 += x1; x1 = rotl32(x1, r); x1 ^= x0; }
  TF_RND(13) TF_RND(15) TF_RND(26) TF_RND(6)
  x0 += K1; x1 += K2 + 1u;
  TF_RND(17) TF_RND(29) TF_RND(16) TF_RND(24)
  x0 += K2; x1 += K0 + 2u;
  TF_RND(13) TF_RND(15) TF_RND(26) TF_RND(6)
  x0 += K0; x1 += K1 + 3u;
  TF_RND(17) TF_RND(29) TF_RND(16) TF_RND(24)
  x0 += K1; x1 += K2 + 4u;
  TF_RND(13) TF_RND(15) TF_RND(26) TF_RND(6)
  x0 += K2; x1 += K0 + 5u;
#undef TF_RND
  return x0 ^ x1;
}

// round-to-nearest-even fp32 -> bf16 split: x = hi + lo (+ ~2^-17 residual)
__device__ inline void bf16split(float x, short& hi, short& lo) {
  uint32_t u = __float_as_uint(x);
  uint32_t h = (u + 0x7FFFu + ((u >> 16) & 1u)) >> 16;
  float rem = x - __uint_as_float(h << 16);
  uint32_t ur = __float_as_uint(rem);
  uint32_t l = (ur + 0x7FFFu + ((ur >> 16) & 1u)) >> 16;
  hi = (short)h; lo = (short)l;
}

__device__ inline float bred_sum(float v, volatile float* tmp, int tid) {
#pragma unroll
  for (int o = 32; o; o >>= 1) v += __shfl_xor(v, o, 64);
  __syncthreads();
  if ((tid & 63) == 0) tmp[tid >> 6] = v;
  __syncthreads();
  return tmp[0] + tmp[1] + tmp[2] + tmp[3];
}

__device__ inline float bred_max(float v, volatile float* tmp, int tid) {
#pragma unroll
  for (int o = 32; o; o >>= 1) v = fmaxf(v, __shfl_xor(v, o, 64));
  __syncthreads();
  if ((tid & 63) == 0) tmp[tid >> 6] = v;
  __syncthreads();
  return fmaxf(fmaxf(tmp[0], tmp[1]), fmaxf(tmp[2], tmp[3]));
}

// joint (a,b) sum-reduce: one pair of barriers for two values
__device__ inline void bred_sum2(float& a, float& b, volatile float* tmp, int tid) {
#pragma unroll
  for (int o = 32; o; o >>= 1) { a += __shfl_xor(a, o, 64); b += __shfl_xor(b, o, 64); }
  __syncthreads();
  if ((tid & 63) == 0) { int w2 = (tid >> 6) * 2; tmp[w2] = a; tmp[w2 + 1] = b; }
  __syncthreads();
  a = tmp[0] + tmp[2] + tmp[4] + tmp[6];
  b = tmp[1] + tmp[3] + tmp[5] + tmp[7];
}

// joint (a,b,c) int sum-reduce
__device__ inline void bred3_i(int& a, int& b, int& c, volatile int* tmp, int tid) {
#pragma unroll
  for (int o = 32; o; o >>= 1) {
    a += __shfl_xor(a, o, 64);
    b += __shfl_xor(b, o, 64);
    c += __shfl_xor(c, o, 64);
  }
  __syncthreads();
  if ((tid & 63) == 0) { int w3 = (tid >> 6) * 3; tmp[w3] = a; tmp[w3 + 1] = b; tmp[w3 + 2] = c; }
  __syncthreads();
  a = tmp[0] + tmp[3] + tmp[6] + tmp[9];
  b = tmp[1] + tmp[4] + tmp[7] + tmp[10];
  c = tmp[2] + tmp[5] + tmp[8] + tmp[11];
}

// ------------------- kernel 0: transpose + bf16-split W1 -> W1T hi/lo in ws
// W1T layout: [HP][DD] bf16 row-major (h-major, k contiguous); h>=HH rows are 0.

__global__ __launch_bounds__(256) void k0_prep(const float* __restrict__ W1,
                                               short* __restrict__ Whi,
                                               short* __restrict__ Wlo) {
  int idx = blockIdx.x * 256 + threadIdx.x;   // < HP*DD
  int h = idx >> 8, k = idx & 255;
  float v = (h < HH) ? W1[k * HH + h] : 0.0f;
  short hi, lo;
  bf16split(v, hi, lo);
  Whi[idx] = hi;
  Wlo[idx] = lo;
}

// ------------------- kernel 1: mask+LN+split-bf16 MFMA MLP -> scores
// 512 threads (8 waves) per 64-row tile; each wave owns 3 h-tiles
// (24 tiles / 8 waves) and all 4 M-tiles. 64 KB LDS -> 2 blocks/CU.
// R3: (1) k0 loop fully unrolled -> scheduler can hoist B loads / LDS frag
// reads across iterations (all offsets fold to immediates); (2) prologue
// global loads hoisted ahead of LN (1 memory round trip instead of 4).
// A (LN'd activations) stored in LDS in MFMA A-fragment order:
// slot(mt,k0,q,i) = mt*512 + k0*64 + q*16 + (i^k0)   (16B units, XOR de-bank)
// holds A[row=mt*16+i][k = k0*32 + q*8 + j], j=0..7.

__global__ __launch_bounds__(512, 4) void k1_mfma(
    const float* __restrict__ emb, const float* __restrict__ attn,
    const float* __restrict__ gamma, const float* __restrict__ beta,
    const short* __restrict__ Whi, const float* __restrict__ b1,
    const float* __restrict__ W2, const float* __restrict__ b2,
    float* __restrict__ scores) {
  __shared__ short Ahi[16384];   // 32 KB
  __shared__ short Alo[16384];   // 32 KB  (total 64 KB exactly)

  const int bid = blockIdx.x;
  const int b = bid >> 6;             // 64 row-tiles per batch row
  const int t0 = (bid & 63) * 64;
  const int tid = threadIdx.x;
  const int w = tid >> 6;             // wave id 0..7
  const int lane = tid & 63;

  // prefix mask: first row masked -> whole 64-row tile masked
  if (attn[(size_t)b * TT + t0] == 0.0f) {
    if (tid < 64) scores[(size_t)b * TT + t0 + tid] = NEGV;
    return;
  }

  // ---------------- prologue: LN 2 rows per wave-iteration, write A frags
  {
    const int half = lane >> 5;        // which of the 2 rows
    const int g = lane & 31;           // 8-col group within row
    const int k0g = g >> 2, qg = g & 3;
    float gg[8], bb[8];
#pragma unroll
    for (int j = 0; j < 8; ++j) { gg[j] = gamma[g * 8 + j]; bb[j] = beta[g * 8 + j]; }

    // hoist ALL global loads first: one latency round trip, not four
    float a4[4];
    float4 xA4[4], xB4[4];
#pragma unroll
    for (int it = 0; it < 4; ++it) {
      const int il = w * 8 + it * 2 + half;          // local row 0..63
      const size_t rowoff = (size_t)b * TT + t0 + il;
      a4[it] = attn[rowoff];
      const float* ep = emb + rowoff * DD + g * 8;
      xA4[it] = *(const float4*)ep;
      xB4[it] = *(const float4*)(ep + 4);
    }

#pragma unroll
    for (int it = 0; it < 4; ++it) {
      const int il = w * 8 + it * 2 + half;
      const float a = a4[it];
      float x[8];
      x[0] = xA4[it].x * a; x[1] = xA4[it].y * a; x[2] = xA4[it].z * a; x[3] = xA4[it].w * a;
      x[4] = xB4[it].x * a; x[5] = xB4[it].y * a; x[6] = xB4[it].z * a; x[7] = xB4[it].w * a;
      float s = 0.f, ss = 0.f;
#pragma unroll
      for (int j = 0; j < 8; ++j) { s += x[j]; ss += x[j] * x[j]; }
#pragma unroll
      for (int o = 16; o; o >>= 1) { s += __shfl_xor(s, o, 32); ss += __shfl_xor(ss, o, 32); }
      const float mu = s * (1.0f / DD);
      const float rs = 1.0f / sqrtf(ss * (1.0f / DD) - mu * mu + 1e-5f);

      short8 h8, l8;
#pragma unroll
      for (int j = 0; j < 8; ++j) {
        float y = (x[j] - mu) * rs * gg[j] + bb[j];
        short hi, lo;
        bf16split(y, hi, lo);
        h8[j] = hi; l8[j] = lo;
      }
      const int i15 = il & 15, mt = il >> 4;
      const int slot = mt * 512 + k0g * 64 + qg * 16 + (i15 ^ k0g);
      *(short8*)&Ahi[slot * 8] = h8;
      *(short8*)&Alo[slot * 8] = l8;
    }
  }
  __syncthreads();

  // ---------------- K-loop: wave w owns h-tiles {3w .. 3w+2}, all 4 M-tiles
  const int r = lane & 15, q = lane >> 4;
  f32x4 acc[3][4];
#pragma unroll
  for (int j = 0; j < 3; ++j)
#pragma unroll
    for (int mt = 0; mt < 4; ++mt) acc[j][mt] = (f32x4){0.f, 0.f, 0.f, 0.f};

  int hb[3];
#pragma unroll
  for (int j = 0; j < 3; ++j) hb[j] = ((w * 3 + j) * 16 + r) * 256 + q * 8;

  // fully unrolled: all LDS slots and B offsets become immediates; the
  // scheduler hoists next-iteration loads under current MFMAs.
#pragma unroll
  for (int k0 = 0; k0 < 8; ++k0) {
    short8 ahi[4], alo[4];
#pragma unroll
    for (int mt = 0; mt < 4; ++mt) {
      const int slot = mt * 512 + k0 * 64 + q * 16 + (r ^ k0);
      ahi[mt] = *(const short8*)&Ahi[slot * 8];
      alo[mt] = *(const short8*)&Alo[slot * 8];
    }
#pragma unroll
    for (int j = 0; j < 3; ++j) {
      const short* bp = Whi + hb[j] + k0 * 32;
      short8 bhi = *(const short8*)bp;
      short8 blo = *(const short8*)(bp + HP * DD);   // Wlo follows Whi
#pragma unroll
      for (int mt = 0; mt < 4; ++mt) {
        acc[j][mt] = __builtin_amdgcn_mfma_f32_16x16x32_bf16(ahi[mt], bhi, acc[j][mt], 0, 0, 0);
        acc[j][mt] = __builtin_amdgcn_mfma_f32_16x16x32_bf16(ahi[mt], blo, acc[j][mt], 0, 0, 0);
        acc[j][mt] = __builtin_amdgcn_mfma_f32_16x16x32_bf16(alo[mt], bhi, acc[j][mt], 0, 0, 0);
      }
    }
  }

  // ---------------- epilogue: gelu -> *W2; sum over j per-lane FIRST,
  // then one 4-level shfl reduce per (mt,rr).
  // C/D layout: col(h within tile) = lane&15, row = q*4 + reg  [m89/m91]
  float part[4][4];
#pragma unroll
  for (int mt = 0; mt < 4; ++mt)
#pragma unroll
    for (int rr = 0; rr < 4; ++rr) part[mt][rr] = 0.f;

#pragma unroll
  for (int j = 0; j < 3; ++j) {
    const int h = (w * 3 + j) * 16 + r;
    const float w2v = (h < HH) ? W2[h] : 0.f;
    const float b1v = (h < HH) ? b1[h] : 0.f;
#pragma unroll
    for (int mt = 0; mt < 4; ++mt)
#pragma unroll
      for (int rr = 0; rr < 4; ++rr)
        part[mt][rr] += gelu_fast(acc[j][mt][rr] + b1v) * w2v;
  }

  float sacc[4][4];
#pragma unroll
  for (int mt = 0; mt < 4; ++mt)
#pragma unroll
    for (int rr = 0; rr < 4; ++rr) {
      float v = part[mt][rr];
      v += __shfl_xor(v, 1, 64);
      v += __shfl_xor(v, 2, 64);
      v += __shfl_xor(v, 4, 64);
      v += __shfl_xor(v, 8, 64);
      sacc[mt][rr] = v;
    }

  __syncthreads();                         // all waves done reading A from LDS
  float* sred = (float*)Ahi;               // overlap: 512 floats
  if (r == 0) {
#pragma unroll
    for (int mt = 0; mt < 4; ++mt)
#pragma unroll
      for (int rr = 0; rr < 4; ++rr)
        sred[w * 64 + mt * 16 + q * 4 + rr] = sacc[mt][rr];
  }
  __syncthreads();

  if (tid < 64) {
    float sc = b2[0];
#pragma unroll
    for (int ww = 0; ww < 8; ++ww) sc += sred[ww * 64 + tid];
    float a = attn[(size_t)b * TT + t0 + tid];
    scores[(size_t)b * TT + t0 + tid] = (a != 0.f) ? sc : NEGV;
  }
}

// ---------------- kernel 2: per batch row — entmax15, gumbel top-k, z/g/tv
// Newton for entmax tau (18 rounds, joint f/g reduce); 2-bit radix select
// (16 rounds, joint 3-counter reduce). Proven correct in R2.

__global__ __launch_bounds__(256) void k2_select(
    const float* __restrict__ attn, float* __restrict__ out, float* __restrict__ row_tv) {
  __shared__ float gs[TT];
  __shared__ float ftmp[8];
  __shared__ int itmp[12];

  const int b = blockIdx.x, tid = threadIdx.x;
  const float* arow = attn + (size_t)b * TT;
  float* zrow = out + (size_t)b * TT;
  float* grow = out + (size_t)BB * TT + (size_t)b * TT;  // holds scores right now

  float x_loc[16], a_loc[16];
  uint32_t key_loc[16];
  float cnt = 0.0f, mx = -3.4e38f;
#pragma unroll
  for (int i = 0; i < 16; ++i) {
    int t = tid + i * 256;
    float s = grow[t];
    float a = arow[t];
    a_loc[i] = a;
    x_loc[i] = s;
    cnt += a;
    mx = fmaxf(mx, s);
    uint32_t bits = threefry_bits((uint32_t)(b * TT + t));
    float u = __uint_as_float(0x3F800000u | (bits >> 9)) - 1.0f;
    float gum = -logf(1e-6f - logf(u + 1e-6f));
    float pert = (a != 0.0f ? s : 0.0f) + gum;
    uint32_t fb = __float_as_uint(pert);
    uint32_t msk = ((int32_t)fb < 0) ? 0xFFFFFFFFu : 0x80000000u;
    key_loc[i] = fb ^ msk;
  }
  float t_eff = bred_sum(cnt, ftmp, tid);
  mx = bred_max(mx, ftmp, tid);

#pragma unroll
  for (int i = 0; i < 16; ++i) x_loc[i] = (x_loc[i] - mx) * 0.5f;

  // Newton for tau: f(tau) = sum (x-tau)_+^2, f'(tau) = -2 sum (x-tau)_+
  float tau = -1.0f;
  for (int it = 0; it < 18; ++it) {
    float f = 0.0f, g = 0.0f;
#pragma unroll
    for (int i = 0; i < 16; ++i) {
      float d = x_loc[i] - tau;
      if (d > 0.0f) { f = fmaf(d, d, f); g += d; }
    }
    bred_sum2(f, g, ftmp, tid);
    tau = fminf(tau + (f - 1.0f) / (2.0f * g), -0.015625f);
  }

  float kf = rintf(0.3f * t_eff);
  kf = fminf(fmaxf(kf, 1.0f), fmaxf(t_eff, 1.0f));
  int kk = (int)kf;

  // 2-bit MSD radix select for the k-th largest key
  uint32_t prefix = 0u;
  for (int bit = 30; bit >= 0; bit -= 2) {
    uint32_t ph = (prefix >> 2) >> bit;          // two-step shift: defined at bit=30
    int c1 = 0, c2 = 0, c3 = 0;
#pragma unroll
    for (int i = 0; i < 16; ++i) {
      uint32_t kb = key_loc[i];
      bool m = (((kb >> 2) >> bit) == ph);
      uint32_t d = (kb >> bit) & 3u;
      c1 += (int)(m && d >= 1u);
      c2 += (int)(m && d >= 2u);
      c3 += (int)(m && d == 3u);
    }
    bred3_i(c1, c2, c3, itmp, tid);
    uint32_t dig;
    if (c3 >= kk) dig = 3u;
    else if (c2 >= kk) { dig = 2u; kk -= c3; }
    else if (c1 >= kk) { dig = 1u; kk -= c2; }
    else { dig = 0u; kk -= c1; }
    prefix |= dig << bit;
  }
  const uint32_t thr = prefix;

#pragma unroll
  for (int i = 0; i < 16; ++i) {
    int t = tid + i * 256;
    float d = x_loc[i] - tau;
    float z = (d > 0.0f) ? d * d : 0.0f;
    z *= a_loc[i];
    float h = (key_loc[i] >= thr) ? a_loc[i] : 0.0f;
    float g = (h - z) + z;
    zrow[t] = z;
    gs[t] = g;
  }
  __syncthreads();

  float tvn = 0.0f, tvd = 0.0f;
#pragma unroll
  for (int i = 0; i < 16; ++i) {
    int t = tid + i * 256;
    grow[t] = gs[t];
    if (t > 0) {
      float valid = arow[t] * arow[t - 1];
      tvn += fabsf(gs[t] - gs[t - 1]) * valid;
      tvd += valid;
    }
  }
  tvn = bred_sum(tvn, ftmp, tid);
  tvd = bred_sum(tvd, ftmp, tid);
  if (tid == 0) row_tv[b] = tvn / fmaxf(tvd, 1.0f);
}

// ------------------------------------------------- kernel 3: reg scalar

__global__ __launch_bounds__(64) void k3_final(const float* __restrict__ row_tv,
                                               float* __restrict__ out) {
  float v = row_tv[threadIdx.x];
#pragma unroll
  for (int o = 32; o; o >>= 1) v += __shfl_xor(v, o, 64);
  if (threadIdx.x == 0) out[2 * BB * TT] = 0.1f * (v * (1.0f / BB));
}

// -------------------------------------------------------------- launcher

extern "C" void kernel_launch(void* const* d_in, const int* in_sizes, int n_in,
                              void* d_out, int out_size, void* d_ws, size_t ws_size,
                              hipStream_t stream) {
  const float* emb   = (const float*)d_in[0];
  const float* attn  = (const float*)d_in[1];
  const float* gamma = (const float*)d_in[2];
  const float* beta  = (const float*)d_in[3];
  const float* W1    = (const float*)d_in[4];
  const float* b1    = (const float*)d_in[5];
  const float* W2    = (const float*)d_in[6];
  const float* b2    = (const float*)d_in[7];
  float* out = (float*)d_out;

  float* row_tv = (float*)d_ws;                        // 64 floats
  short* Whi = (short*)((char*)d_ws + 512);            // [HP*DD] bf16 hi
  short* Wlo = Whi + HP * DD;                          // [HP*DD] bf16 lo

  k0_prep<<<dim3(HP * DD / 256), dim3(256), 0, stream>>>(W1, Whi, Wlo);
  k1_mfma<<<dim3(BB * TT / 64), dim3(512), 0, stream>>>(
      emb, attn, gamma, beta, Whi, b1, W2, b2, out + (size_t)BB * TT);
  k2_select<<<dim3(BB), dim3(256), 0, stream>>>(attn, out, row_tv);
  k3_final<<<dim3(1), dim3(64), 0, stream>>>(row_tv, out);
}